// Round 11
// baseline (63.409 us; speedup 1.0000x reference)
//
#include <hip/hip_runtime.h>

// Problem constants: B=32, L=4096, C=21, D=512, K=24, LO=8, M=7, TAO=12
#define LL 4096
#define CC 21
#define TT 64            // t-tile
#define NTB 2            // tiles per block (both staged up-front)
#define XSTR 156         // LDS time stride: mult of 4 -> 16B-aligned windows
#define STG_N (150 * CC) // 3150 staged floats per tile
#define NSTG 13          // ceil(3150/256)

typedef float v2f __attribute__((ext_vector_type(2)));
typedef float v4f __attribute__((ext_vector_type(4)));

__device__ __forceinline__ v2f fma2(v2f a, v2f b, v2f c) {
    return __builtin_elementwise_fma(a, b, c);
}

// LDS-only barrier: lgkmcnt(0) + s_barrier. Global stores/loads stay in flight.
#define RAW_BARRIER() do {                                  \
    asm volatile("s_waitcnt lgkmcnt(0)" ::: "memory");      \
    __builtin_amdgcn_s_barrier();                           \
} while (0)

// Issue the 13 global loads for the tile with conv base `baset` (= t0-85).
// Branchless wrap: ofs = baset*21 + e, corrected by ±LL*21 via e-thresholds.
__device__ __forceinline__ void prefetch_tile(const float* __restrict__ xb,
                                              int baset, int tid, float* pf) {
    const int lo21 = (0 - baset) * CC;
    const int hi21 = (LL - baset) * CC;
    #pragma unroll
    for (int i = 0; i < NSTG; ++i) {
        int e = tid + 256 * i;
        if (e < STG_N) {
            int ofs = baset * CC + e;
            if (e < lo21)  ofs += LL * CC;
            if (e >= hi21) ofs -= LL * CC;
            pf[i] = xb[ofs];
        }
    }
}

__device__ __forceinline__ void write_tile(float* __restrict__ xsb, int tid,
                                           const float* pf) {
    #pragma unroll
    for (int i = 0; i < NSTG; ++i) {
        int e = tid + 256 * i;
        if (e < STG_N) {
            int s = e / CC, c2 = e - s * CC;
            xsb[c2 * XSTR + s] = pf[i];
        }
    }
}

// Each lane computes a 4-d x 16-t output tile; a wave's 64 lanes cover a
// contiguous 256-float d-range -> every store is a fully dense 1 KB.
// EDGE: zero-mask conv positions (t0+tg*16+s-1) mod L < 84.
template<bool EDGE>
__device__ __forceinline__ void compute_item(
    const float* __restrict__ xrow, const float* __restrict__ wtc,
    const float* __restrict__ biasc, float* __restrict__ outp,
    int vo0, int d0, int tg, int t0)
{
    v2f acc[16][2];
    {
        v2f b0 = { biasc[vo0],     biasc[vo0 + 1] };
        v2f b1 = { biasc[vo0 + 2], biasc[vo0 + 3] };
        #pragma unroll
        for (int ti = 0; ti < 16; ++ti) { acc[ti][0] = b0; acc[ti][1] = b1; }
    }

    const int base = tg * 16 + 84;   // mod 4 == 0 -> 16B-aligned windows

    #pragma unroll 1
    for (int j = 0; j < 8; ++j) {
        const float* wp = &wtc[96 * j + vo0];          // 16B-aligned
        v4f w0 = *reinterpret_cast<const v4f*>(wp);
        v4f w1 = *reinterpret_cast<const v4f*>(wp + 32);
        v4f w2 = *reinterpret_cast<const v4f*>(wp + 64);

        // sliding window: 18 aligned slots -> 4x b128 + 1x b64
        const float* vp = xrow + (base - 12 * j);
        v4f va = *reinterpret_cast<const v4f*>(vp);
        v4f vb = *reinterpret_cast<const v4f*>(vp + 4);
        v4f vc = *reinterpret_cast<const v4f*>(vp + 8);
        v4f vd = *reinterpret_cast<const v4f*>(vp + 12);
        v2f ve = *reinterpret_cast<const v2f*>(vp + 16);
        float v[18] = { va.x, va.y, va.z, va.w, vb.x, vb.y, vb.z, vb.w,
                        vc.x, vc.y, vc.z, vc.w, vd.x, vd.y, vd.z, vd.w,
                        ve.x, ve.y };
        if (EDGE) {
            #pragma unroll
            for (int s = 0; s < 18; ++s)
                if (((t0 + tg * 16 + s - 1) & (LL - 1)) < 84) v[s] = 0.0f;
        }

        #pragma unroll
        for (int ti = 0; ti < 16; ++ti) {
            v2f vv, w;
            vv.x = vv.y = v[ti];
            w.x = w0.x; w.y = w0.y; acc[ti][0] = fma2(vv, w, acc[ti][0]);
            w.x = w0.z; w.y = w0.w; acc[ti][1] = fma2(vv, w, acc[ti][1]);
            vv.x = vv.y = v[ti + 1];
            w.x = w1.x; w.y = w1.y; acc[ti][0] = fma2(vv, w, acc[ti][0]);
            w.x = w1.z; w.y = w1.w; acc[ti][1] = fma2(vv, w, acc[ti][1]);
            vv.x = vv.y = v[ti + 2];
            w.x = w2.x; w.y = w2.y; acc[ti][0] = fma2(vv, w, acc[ti][0]);
            w.x = w2.z; w.y = w2.w; acc[ti][1] = fma2(vv, w, acc[ti][1]);
        }
    }

    #pragma unroll
    for (int ti = 0; ti < 16; ++ti) {
        v4f r = { acc[ti][0].x, acc[ti][0].y, acc[ti][1].x, acc[ti][1].y };
        float* p = outp + (size_t)(tg * 16 + ti) * 512 + d0;
        __builtin_nontemporal_store(r, reinterpret_cast<v4f*>(p));
    }
}

__global__ __launch_bounds__(256)
__attribute__((amdgpu_waves_per_eu(4, 4)))
void delay_fir_kernel(
    const float* __restrict__ x,       // [32][4096][21]
    const float* __restrict__ conv_w,  // [24][8][3]
    const float* __restrict__ conv_b,  // [24]
    const float* __restrict__ lw,      // [8][8][3]
    const float* __restrict__ lb,      // [8]
    float* __restrict__ out)           // [32][4096][512]
{
    __shared__ __align__(16) float xs[2][CC * XSTR];
    __shared__ __align__(16) float wtc[24 * 32];
    __shared__ float biasc[32];

    const int tid   = threadIdx.x;
    const int b     = blockIdx.y;
    const int tbase = blockIdx.x * (TT * NTB);

    // stage weights once per block, transposed to wtc[jk][vo]
    for (int e = tid; e < 24 * 32; e += 256) {
        int jk = e >> 5, vo = e & 31;
        wtc[e] = (vo < 24) ? conv_w[vo * 24 + jk] : lw[(vo - 24) * 24 + jk];
    }
    if (tid < 32) biasc[tid] = (tid < 24) ? conv_b[tid] : lb[tid - 24];

    const float* xb = x + (size_t)b * (LL * CC);

    // stage BOTH tiles up-front -> single barrier per block, no pf live range
    // across compute, no mid-loop sync.
    {
        float pf0[NSTG], pf1[NSTG];
        prefetch_tile(xb, tbase - 85, tid, pf0);
        prefetch_tile(xb, tbase + TT - 85, tid, pf1);
        write_tile(xs[0], tid, pf0);
        write_tile(xs[1], tid, pf1);
    }
    RAW_BARRIER();

    // lane -> d mapping: wave w owns d-half h=w&1; lane l covers d0=256h+4l..+3
    const int l  = tid & 63;
    const int w  = tid >> 6;
    const int d0 = 256 * (w & 1) + 4 * l;
    int c, vo0;
    if (d0 >= 504) { c = 20; vo0 = 24 + (d0 - 504); }   // leftout rows 24..31
    else           { c = d0 / 24; vo0 = d0 - c * 24; }

    #pragma unroll 1
    for (int tix = 0; tix < NTB; ++tix) {
        const int t0 = tbase + tix * TT;
        const float* xrow = &xs[tix][c * XSTR];
        float* outp = out + ((size_t)b * LL + t0) * 512;
        const bool edge = (t0 == 0) | (t0 == TT) | (t0 == LL - TT);
        #pragma unroll 1
        for (int it = 0; it < 2; ++it) {
            int tg = it * 2 + (w >> 1);   // wave-uniform t-subgroup (0..3)
            if (edge) compute_item<true >(xrow, wtc, biasc, outp, vo0, d0, tg, t0);
            else      compute_item<false>(xrow, wtc, biasc, outp, vo0, d0, tg, t0);
        }
    }
}

extern "C" void kernel_launch(void* const* d_in, const int* in_sizes, int n_in,
                              void* d_out, int out_size, void* d_ws, size_t ws_size,
                              hipStream_t stream) {
    const float* x      = (const float*)d_in[0];
    const float* conv_w = (const float*)d_in[1];
    const float* conv_b = (const float*)d_in[2];
    const float* lw     = (const float*)d_in[3];
    const float* lb     = (const float*)d_in[4];
    float* out = (float*)d_out;

    dim3 grid(LL / (TT * NTB), 32);  // 1024 blocks = 4/CU x 256 CU, one round
    delay_fir_kernel<<<grid, 256, 0, stream>>>(x, conv_w, conv_b, lw, lb, out);
}

// Round 12
// 56.127 us; speedup vs baseline: 1.1297x; 1.1297x over previous
//
#include <hip/hip_runtime.h>

// Problem constants: B=32, L=4096, C=21, D=512, K=24, LO=8, M=7, TAO=12
#define LL 4096
#define CC 21
#define TT 128                 // t-tile per block (single tile)
#define XSTR 220               // mult of 4 (aligned windows); 28*c bank offset -> worst 2-way
#define STG_SLOTS (TT + 86)    // 214 staged time slots
#define STG_N (STG_SLOTS * CC) // 4494 floats
#define NSTG 18                // ceil(4494/256)

typedef float v2f __attribute__((ext_vector_type(2)));
typedef float v4f __attribute__((ext_vector_type(4)));

__device__ __forceinline__ v2f fma2(v2f a, v2f b, v2f c) {
    return __builtin_elementwise_fma(a, b, c);
}

// LDS-only barrier: lgkmcnt(0) + s_barrier. Global stores/loads stay in flight.
#define RAW_BARRIER() do {                                  \
    asm volatile("s_waitcnt lgkmcnt(0)" ::: "memory");      \
    __builtin_amdgcn_s_barrier();                           \
} while (0)

// Issue the 18 global loads for the tile with conv base `baset` (= t0-85).
// Branchless wrap: ofs = baset*21 + e, corrected by ±LL*21 via e-thresholds.
__device__ __forceinline__ void prefetch_tile(const float* __restrict__ xb,
                                              int baset, int tid, float* pf) {
    const int lo21 = (0 - baset) * CC;
    const int hi21 = (LL - baset) * CC;
    #pragma unroll
    for (int i = 0; i < NSTG; ++i) {
        int e = tid + 256 * i;
        if (e < STG_N) {
            int ofs = baset * CC + e;
            if (e < lo21)  ofs += LL * CC;
            if (e >= hi21) ofs -= LL * CC;
            pf[i] = xb[ofs];
        }
    }
}

__device__ __forceinline__ void write_tile(float* __restrict__ xsb, int tid,
                                           const float* pf) {
    #pragma unroll
    for (int i = 0; i < NSTG; ++i) {
        int e = tid + 256 * i;
        if (e < STG_N) {
            int s = e / CC, c2 = e - s * CC;
            xsb[c2 * XSTR + s] = pf[i];
        }
    }
}

// 16-row FMA block for one j-tap triple (k=0..2), 4 d-outputs as 2x v2f.
__device__ __forceinline__ void fma_block(const float* __restrict__ v,
                                          v4f w0, v4f w1, v4f w2,
                                          v2f acc[16][2]) {
    #pragma unroll
    for (int ti = 0; ti < 16; ++ti) {
        v2f vv, w;
        vv.x = vv.y = v[ti];
        w.x = w0.x; w.y = w0.y; acc[ti][0] = fma2(vv, w, acc[ti][0]);
        w.x = w0.z; w.y = w0.w; acc[ti][1] = fma2(vv, w, acc[ti][1]);
        vv.x = vv.y = v[ti + 1];
        w.x = w1.x; w.y = w1.y; acc[ti][0] = fma2(vv, w, acc[ti][0]);
        w.x = w1.z; w.y = w1.w; acc[ti][1] = fma2(vv, w, acc[ti][1]);
        vv.x = vv.y = v[ti + 2];
        w.x = w2.x; w.y = w2.y; acc[ti][0] = fma2(vv, w, acc[ti][0]);
        w.x = w2.z; w.y = w2.w; acc[ti][1] = fma2(vv, w, acc[ti][1]);
    }
}

// Each lane computes a 4-d x 16-t output tile; a wave's 64 lanes cover a
// contiguous 256-float d-range -> every store is a fully dense 1 KB.
// Non-EDGE: sliding v-window (reuse 6 of 18 slots across j; 3 new b128/j).
// EDGE (2 blocks only): full 18-slot reload + tap mask each j (the mask is
// per-tap, so shifted values can't be reused).
template<bool EDGE>
__device__ __forceinline__ void compute_item(
    const float* __restrict__ xrow, const float* __restrict__ wtc,
    const float* __restrict__ biasc, float* __restrict__ outp,
    int vo0, int d0, int tg, int t0)
{
    v2f acc[16][2];
    {
        v2f b0 = { biasc[vo0],     biasc[vo0 + 1] };
        v2f b1 = { biasc[vo0 + 2], biasc[vo0 + 3] };
        #pragma unroll
        for (int ti = 0; ti < 16; ++ti) { acc[ti][0] = b0; acc[ti][1] = b1; }
    }

    const int base = tg * 16 + 84;   // mod 4 == 0 -> 16B-aligned windows
    float v[18];

    // j = 0: full window load
    {
        const float* vp = xrow + base;
        v4f va = *reinterpret_cast<const v4f*>(vp);
        v4f vb = *reinterpret_cast<const v4f*>(vp + 4);
        v4f vc = *reinterpret_cast<const v4f*>(vp + 8);
        v4f vd = *reinterpret_cast<const v4f*>(vp + 12);
        v2f ve = *reinterpret_cast<const v2f*>(vp + 16);
        v[0]=va.x; v[1]=va.y; v[2]=va.z; v[3]=va.w;
        v[4]=vb.x; v[5]=vb.y; v[6]=vb.z; v[7]=vb.w;
        v[8]=vc.x; v[9]=vc.y; v[10]=vc.z; v[11]=vc.w;
        v[12]=vd.x; v[13]=vd.y; v[14]=vd.z; v[15]=vd.w;
        v[16]=ve.x; v[17]=ve.y;
        if (EDGE) {
            #pragma unroll
            for (int s = 0; s < 18; ++s)
                if (((t0 + tg * 16 + s - 1) & (LL - 1)) < 84) v[s] = 0.0f;
        }
        const float* wp = &wtc[vo0];
        fma_block(v, *reinterpret_cast<const v4f*>(wp),
                     *reinterpret_cast<const v4f*>(wp + 32),
                     *reinterpret_cast<const v4f*>(wp + 64), acc);
    }

    #pragma unroll 1
    for (int j = 1; j < 8; ++j) {
        const float* vp = xrow + (base - 12 * j);
        if (EDGE) {
            v4f va = *reinterpret_cast<const v4f*>(vp);
            v4f vb = *reinterpret_cast<const v4f*>(vp + 4);
            v4f vc = *reinterpret_cast<const v4f*>(vp + 8);
            v4f vd = *reinterpret_cast<const v4f*>(vp + 12);
            v2f ve = *reinterpret_cast<const v2f*>(vp + 16);
            v[0]=va.x; v[1]=va.y; v[2]=va.z; v[3]=va.w;
            v[4]=vb.x; v[5]=vb.y; v[6]=vb.z; v[7]=vb.w;
            v[8]=vc.x; v[9]=vc.y; v[10]=vc.z; v[11]=vc.w;
            v[12]=vd.x; v[13]=vd.y; v[14]=vd.z; v[15]=vd.w;
            v[16]=ve.x; v[17]=ve.y;
            #pragma unroll
            for (int s = 0; s < 18; ++s)
                if (((t0 + tg * 16 + s - 1) & (LL - 1)) < 84) v[s] = 0.0f;
        } else {
            // slide down by 12: old taps 0..5 become taps 12..17
            float s0 = v[0], s1 = v[1], s2 = v[2], s3 = v[3], s4 = v[4], s5 = v[5];
            v4f va = *reinterpret_cast<const v4f*>(vp);
            v4f vb = *reinterpret_cast<const v4f*>(vp + 4);
            v4f vc = *reinterpret_cast<const v4f*>(vp + 8);
            v[0]=va.x; v[1]=va.y; v[2]=va.z; v[3]=va.w;
            v[4]=vb.x; v[5]=vb.y; v[6]=vb.z; v[7]=vb.w;
            v[8]=vc.x; v[9]=vc.y; v[10]=vc.z; v[11]=vc.w;
            v[12]=s0; v[13]=s1; v[14]=s2; v[15]=s3; v[16]=s4; v[17]=s5;
        }
        const float* wp = &wtc[96 * j + vo0];
        fma_block(v, *reinterpret_cast<const v4f*>(wp),
                     *reinterpret_cast<const v4f*>(wp + 32),
                     *reinterpret_cast<const v4f*>(wp + 64), acc);
    }

    #pragma unroll
    for (int ti = 0; ti < 16; ++ti) {
        v4f r = { acc[ti][0].x, acc[ti][0].y, acc[ti][1].x, acc[ti][1].y };
        float* p = outp + (size_t)(tg * 16 + ti) * 512 + d0;
        *reinterpret_cast<v4f*>(p) = r;
    }
}

__global__ __launch_bounds__(256)
__attribute__((amdgpu_waves_per_eu(4, 4)))
void delay_fir_kernel(
    const float* __restrict__ x,       // [32][4096][21]
    const float* __restrict__ conv_w,  // [24][8][3]
    const float* __restrict__ conv_b,  // [24]
    const float* __restrict__ lw,      // [8][8][3]
    const float* __restrict__ lb,      // [8]
    float* __restrict__ out)           // [32][4096][512]
{
    __shared__ __align__(16) float xs[CC * XSTR];   // single buffer, 18.5 KB
    __shared__ __align__(16) float wtc[24 * 32];
    __shared__ float biasc[32];

    const int tid   = threadIdx.x;
    const int b     = blockIdx.y;
    const int tbase = blockIdx.x * TT;

    // stage weights, transposed to wtc[jk][vo] (vo<24: conv row, 24..31: leftout)
    for (int e = tid; e < 24 * 32; e += 256) {
        int jk = e >> 5, vo = e & 31;
        wtc[e] = (vo < 24) ? conv_w[vo * 24 + jk] : lw[(vo - 24) * 24 + jk];
    }
    if (tid < 32) biasc[tid] = (tid < 24) ? conv_b[tid] : lb[tid - 24];

    const float* xb = x + (size_t)b * (LL * CC);

    // single staging phase: 214 slots, one barrier per block
    {
        float pf[NSTG];
        prefetch_tile(xb, tbase - 85, tid, pf);
        write_tile(xs, tid, pf);
    }
    RAW_BARRIER();

    // lane -> d mapping: wave w owns d-half h=w&1; lane l covers d0=256h+4l..+3
    const int l  = tid & 63;
    const int w  = tid >> 6;
    const int d0 = 256 * (w & 1) + 4 * l;
    const int tpair = w >> 1;
    int c, vo0;
    if (d0 >= 504) { c = 20; vo0 = 24 + (d0 - 504); }   // leftout rows 24..31
    else           { c = d0 / 24; vo0 = d0 - c * 24; }

    const float* xrow = &xs[c * XSTR];
    float* outp = out + ((size_t)b * LL + tbase) * 512;
    const bool edge = (tbase == 0) | (tbase == LL - TT);

    #pragma unroll 1
    for (int it = 0; it < 4; ++it) {
        int tg = it * 2 + tpair;   // wave-uniform t-subgroup (0..7)
        if (edge) compute_item<true >(xrow, wtc, biasc, outp, vo0, d0, tg, tbase);
        else      compute_item<false>(xrow, wtc, biasc, outp, vo0, d0, tg, tbase);
    }
}

extern "C" void kernel_launch(void* const* d_in, const int* in_sizes, int n_in,
                              void* d_out, int out_size, void* d_ws, size_t ws_size,
                              hipStream_t stream) {
    const float* x      = (const float*)d_in[0];
    const float* conv_w = (const float*)d_in[1];
    const float* conv_b = (const float*)d_in[2];
    const float* lw     = (const float*)d_in[3];
    const float* lb     = (const float*)d_in[4];
    float* out = (float*)d_out;

    dim3 grid(LL / TT, 32);  // (32, 32) = 1024 blocks = 4/CU x 256 CU, one round
    delay_fir_kernel<<<grid, 256, 0, stream>>>(x, conv_w, conv_b, lw, lb, out);
}